// Round 7
// baseline (281.198 us; speedup 1.0000x reference)
//
#include <hip/hip_runtime.h>
#include <math.h>

#define L 4096
#define D 1024
#define H 16
#define KV 4
#define DH 64
// G = H/KV = 4

typedef __attribute__((ext_vector_type(8))) short bf16x8;
typedef __attribute__((ext_vector_type(4))) float f32x4;

static __device__ __forceinline__ unsigned short f2bf(float f) {
    unsigned u = __float_as_uint(f);
    u = (u + 0x7FFF + ((u >> 16) & 1)) >> 16;   // RNE
    return (unsigned short)u;
}

#define EXP2F(x) __builtin_amdgcn_exp2f(x)

// async global->LDS, 16B per lane; dst must be wave-uniform base (HW: base + lane*16)
#define GLD16(src, dst) \
    __builtin_amdgcn_global_load_lds((__attribute__((address_space(1))) void*)(src), \
                                     (__attribute__((address_space(3))) void*)(dst), 16, 0, 0)

// ---------------------------------------------------------------------------
// prep: x fp32->bf16, and the four weight transposes (dst[n][k] bf16, K=1024).
// ---------------------------------------------------------------------------
__global__ __launch_bounds__(256) void prep_kernel(
        const float* __restrict__ x,  const float* __restrict__ Wq,
        const float* __restrict__ Wk, const float* __restrict__ Wv,
        const float* __restrict__ Wo,
        unsigned short* __restrict__ xb, unsigned short* __restrict__ WqkvT,
        unsigned short* __restrict__ WoT) {
    const int b = blockIdx.x, tid = threadIdx.x;
    if (b < 4096) {
        int i = (b * 256 + tid) * 4;
        float4 v = *(const float4*)&x[i];
        ushort4 o;
        o.x = f2bf(v.x); o.y = f2bf(v.y); o.z = f2bf(v.z); o.w = f2bf(v.w);
        *(ushort4*)&xb[i] = o;
        return;
    }
    __shared__ float t[32][33];
    const float* src; unsigned short* dst; int N, n0, k0;
    if (b < 5120)      { int tq = b - 4096; src = Wq; dst = WqkvT;                     N = 1024; n0 = (tq & 31) * 32; k0 = (tq >> 5) * 32; }
    else if (b < 5376) { int tq = b - 5120; src = Wk; dst = WqkvT + (size_t)1024*1024; N = 256;  n0 = (tq & 7)  * 32; k0 = (tq >> 3) * 32; }
    else if (b < 5632) { int tq = b - 5376; src = Wv; dst = WqkvT + (size_t)1280*1024; N = 256;  n0 = (tq & 7)  * 32; k0 = (tq >> 3) * 32; }
    else               { int tq = b - 5632; src = Wo; dst = WoT;                       N = 1024; n0 = (tq & 31) * 32; k0 = (tq >> 5) * 32; }
    const int tx = tid & 31, ty = tid >> 5;
    #pragma unroll
    for (int j = 0; j < 4; ++j)
        t[ty + 8 * j][tx] = src[(size_t)(k0 + ty + 8 * j) * N + n0 + tx];
    __syncthreads();
    #pragma unroll
    for (int j = 0; j < 4; ++j)
        dst[(size_t)(n0 + ty + 8 * j) * 1024 + k0 + tx] = f2bf(t[tx][ty + 8 * j]);
}

// ---------------------------------------------------------------------------
// bf16 MFMA GEMM (fp32 out) for the Wo projection.
// ---------------------------------------------------------------------------
__global__ __launch_bounds__(256) void gemm_bf16(const unsigned short* __restrict__ A,
                                                 const unsigned short* __restrict__ BT,
                                                 float* __restrict__ C,
                                                 int M, int N, int K) {
    __shared__ unsigned short As[128 * 32];
    __shared__ unsigned short Bs[128 * 32];

    const int tid  = threadIdx.x;
    const int w    = tid >> 6;
    const int lane = tid & 63;
    const int c    = lane & 15;
    const int quad = lane >> 4;
    const int wy = w >> 1, wx = w & 1;
    const int row0 = blockIdx.y * 128;
    const int col0 = blockIdx.x * 128;

    const int ld_row = w * 16 + (lane >> 2);
    const int ld_col = (lane & 3) * 8;

    f32x4 acc[4][4];
    #pragma unroll
    for (int mt = 0; mt < 4; ++mt)
        #pragma unroll
        for (int nt = 0; nt < 4; ++nt)
            acc[mt][nt] = (f32x4){0.f, 0.f, 0.f, 0.f};

    for (int k0 = 0; k0 < K; k0 += 32) {
        __syncthreads();
        GLD16(&A [(size_t)(row0 + ld_row)      * K + k0 + ld_col], &As[w * 512]);
        GLD16(&A [(size_t)(row0 + ld_row + 64) * K + k0 + ld_col], &As[w * 512 + 2048]);
        GLD16(&BT[(size_t)(col0 + ld_row)      * K + k0 + ld_col], &Bs[w * 512]);
        GLD16(&BT[(size_t)(col0 + ld_row + 64) * K + k0 + ld_col], &Bs[w * 512 + 2048]);
        __syncthreads();

        bf16x8 af[4], bfr[4];
        #pragma unroll
        for (int mt = 0; mt < 4; ++mt)
            af[mt] = *(const bf16x8*)&As[(wy * 64 + mt * 16 + c) * 32 + quad * 8];
        #pragma unroll
        for (int nt = 0; nt < 4; ++nt)
            bfr[nt] = *(const bf16x8*)&Bs[(wx * 64 + nt * 16 + c) * 32 + quad * 8];

        #pragma unroll
        for (int mt = 0; mt < 4; ++mt)
            #pragma unroll
            for (int nt = 0; nt < 4; ++nt)
                acc[mt][nt] = __builtin_amdgcn_mfma_f32_16x16x32_bf16(af[mt], bfr[nt], acc[mt][nt], 0, 0, 0);
    }

    #pragma unroll
    for (int mt = 0; mt < 4; ++mt)
        #pragma unroll
        for (int nt = 0; nt < 4; ++nt)
            #pragma unroll
            for (int r = 0; r < 4; ++r)
                C[(size_t)(row0 + wy * 64 + mt * 16 + quad * 4 + r) * N
                  + col0 + wx * 64 + nt * 16 + c] = acc[mt][nt][r];
}

// ---------------------------------------------------------------------------
// Fused QKV GEMM + RoPE epilogue. (unchanged from R6)
// ---------------------------------------------------------------------------
__global__ __launch_bounds__(256) void gemm_qkv_rope(
        const unsigned short* __restrict__ A,
        const unsigned short* __restrict__ BT,
        unsigned short* __restrict__ qb,
        unsigned short* __restrict__ kbuf,
        unsigned short* __restrict__ vbuf) {
    __shared__ unsigned short As[128 * 32];
    __shared__ unsigned short Bs[128 * 32];

    const int tid  = threadIdx.x;
    const int w    = tid >> 6;
    const int lane = tid & 63;
    const int c    = lane & 15;
    const int quad = lane >> 4;
    const int wy = w >> 1, wx = w & 1;
    const int row0 = blockIdx.y * 128;
    const int col0 = blockIdx.x * 128;

    const int ld_row = w * 16 + (lane >> 2);
    const int ld_col = (lane & 3) * 8;

    f32x4 acc[4][4];
    #pragma unroll
    for (int mt = 0; mt < 4; ++mt)
        #pragma unroll
        for (int nt = 0; nt < 4; ++nt)
            acc[mt][nt] = (f32x4){0.f, 0.f, 0.f, 0.f};

    for (int k0 = 0; k0 < 1024; k0 += 32) {
        __syncthreads();
        GLD16(&A [(size_t)(row0 + ld_row)      * 1024 + k0 + ld_col], &As[w * 512]);
        GLD16(&A [(size_t)(row0 + ld_row + 64) * 1024 + k0 + ld_col], &As[w * 512 + 2048]);
        GLD16(&BT[(size_t)(col0 + ld_row)      * 1024 + k0 + ld_col], &Bs[w * 512]);
        GLD16(&BT[(size_t)(col0 + ld_row + 64) * 1024 + k0 + ld_col], &Bs[w * 512 + 2048]);
        __syncthreads();

        bf16x8 af[4], bfr[4];
        #pragma unroll
        for (int mt = 0; mt < 4; ++mt)
            af[mt] = *(const bf16x8*)&As[(wy * 64 + mt * 16 + c) * 32 + quad * 8];
        #pragma unroll
        for (int nt = 0; nt < 4; ++nt)
            bfr[nt] = *(const bf16x8*)&Bs[(wx * 64 + nt * 16 + c) * 32 + quad * 8];

        #pragma unroll
        for (int mt = 0; mt < 4; ++mt)
            #pragma unroll
            for (int nt = 0; nt < 4; ++nt)
                acc[mt][nt] = __builtin_amdgcn_mfma_f32_16x16x32_bf16(af[mt], bfr[nt], acc[mt][nt], 0, 0, 0);
    }

    const int colb = col0 + wx * 64;
    if (colb < 1280) {
        unsigned short* dst; int hh, hstride; float scale;
        if (colb < 1024) { dst = qb;   hh = colb >> 6;          hstride = H;  scale = 0.18033688011112042f; }
        else             { dst = kbuf; hh = (colb - 1024) >> 6; hstride = KV; scale = 1.0f; }
        #pragma unroll
        for (int nt = 0; nt < 2; ++nt) {
            int d = nt * 16 + c;
            float invf = EXP2F((float)d * -0.4152410118609203f);
            #pragma unroll
            for (int mt = 0; mt < 4; ++mt)
                #pragma unroll
                for (int r = 0; r < 4; ++r) {
                    int l = row0 + wy * 64 + mt * 16 + quad * 4 + r;
                    float ang = (float)l * invf;
                    float sn = __sinf(ang), cs = __cosf(ang);
                    float x1 = acc[mt][nt][r], x2 = acc[mt][nt + 2][r];
                    dst[((size_t)l * hstride + hh) * DH + d]      = f2bf((x1 * cs - x2 * sn) * scale);
                    dst[((size_t)l * hstride + hh) * DH + d + 32] = f2bf((x2 * cs + x1 * sn) * scale);
                }
        }
    } else {
        int vh = (colb - 1280) >> 6;
        #pragma unroll
        for (int mt = 0; mt < 4; ++mt)
            #pragma unroll
            for (int nt = 0; nt < 4; ++nt)
                #pragma unroll
                for (int r = 0; r < 4; ++r) {
                    int l = row0 + wy * 64 + mt * 16 + quad * 4 + r;
                    vbuf[((size_t)l * KV + vh) * DH + nt * 16 + c] = f2bf(acc[mt][nt][r]);
                }
    }
}

// ---------------------------------------------------------------------------
// MFMA attention. Grid (L/32=128, KV=4) = 512 blocks (2/CU), 256 thr.
// Wave w = head kv*4+w, 32 q-rows (qt=0,1). K direct global->regs
// (double-buffered). V staged to swizzled LDS Vt (double-buffered, shared
// by the 4 waves — same kv group). One barrier per key-tile iter.
// Ps wave-private, XOR-swizzled (16B granule, ^c&7): conflict-free.
// ---------------------------------------------------------------------------
__global__ __launch_bounds__(256, 2) void attn_mfma_kernel(
        const unsigned short* __restrict__ qb,
        const unsigned short* __restrict__ kb,
        const unsigned short* __restrict__ vb,
        unsigned short* __restrict__ ob) {
    __shared__ __align__(16) unsigned short Vt[2][64][64];   // [buf][d][key], swizzled
    __shared__ __align__(16) unsigned short Ps[4][32][64];   // [wave][q][key], swizzled

    const int tid  = threadIdx.x;
    const int w    = tid >> 6;
    const int lane = tid & 63;
    const int c    = lane & 15;
    const int quad = lane >> 4;
    const int kv = blockIdx.y;
    const int h  = kv * 4 + w;
    const int q0 = blockIdx.x * 32;

    // Q B-frags: lane n=c -> q row q0+qt*16+c, elems d = kt*32+quad*8+j
    bf16x8 qfrag[2][2];
    #pragma unroll
    for (int qt = 0; qt < 2; ++qt)
        #pragma unroll
        for (int kt = 0; kt < 2; ++kt)
            qfrag[qt][kt] = *(const bf16x8*)&qb[((size_t)(q0 + qt * 16 + c) * H + h) * DH
                                                + kt * 32 + quad * 8];

    f32x4 oacc[2][4];     // [qt][dt]
    f32x4 oones[2];       // [qt] rowsums
    #pragma unroll
    for (int qt = 0; qt < 2; ++qt) {
        oones[qt] = (f32x4){0.f, 0.f, 0.f, 0.f};
        #pragma unroll
        for (int dt = 0; dt < 4; ++dt)
            oacc[qt][dt] = (f32x4){0.f, 0.f, 0.f, 0.f};
    }
    const short one_bf = (short)0x3F80;
    const bf16x8 ones8 = {one_bf, one_bf, one_bf, one_bf, one_bf, one_bf, one_bf, one_bf};

    const int sp = tid & 31, dc = tid >> 5;   // V staging: keys (2sp,2sp+1), d-chunk dc*8
    unsigned short* PsW = &Ps[w][0][0];
    const int xr = c & 7;                      // swizzle xor

    // ---- prefetch iter 0 ----
    int4 vreg0 = *(const int4*)&vb[((size_t)(2 * sp)     * KV + kv) * DH + dc * 8];
    int4 vreg1 = *(const int4*)&vb[((size_t)(2 * sp + 1) * KV + kv) * DH + dc * 8];
    bf16x8 kA[4][2], kB[4][2];
    #pragma unroll
    for (int mt = 0; mt < 4; ++mt)
        #pragma unroll
        for (int kt = 0; kt < 2; ++kt)
            kA[mt][kt] = *(const bf16x8*)&kb[((size_t)(mt * 16 + c) * KV + kv) * DH + kt * 32 + quad * 8];

    auto step = [&](int it, int buf, bf16x8 kc[4][2], bf16x8 kn[4][2]) {
        // ---- write Vt[buf] (swizzled, conflict-free) ----
        {
            const unsigned* pa = (const unsigned*)&vreg0;
            const unsigned* pb = (const unsigned*)&vreg1;
            #pragma unroll
            for (int t = 0; t < 4; ++t) {
                unsigned lo = __builtin_amdgcn_perm(pb[t], pa[t], 0x05040100u);
                unsigned hi = __builtin_amdgcn_perm(pb[t], pa[t], 0x07060302u);
                int dl = dc * 8 + 2 * t, dh = dl + 1;
                *(unsigned*)&Vt[buf][dl][(((sp >> 2) ^ (dl & 7)) << 3) + 2 * (sp & 3)] = lo;
                *(unsigned*)&Vt[buf][dh][(((sp >> 2) ^ (dh & 7)) << 3) + 2 * (sp & 3)] = hi;
            }
        }
        __syncthreads();   // Vt[buf] visible; prior-iter reads complete

        // ---- prefetch next key-tile (overlaps compute below) ----
        int s1 = ((it + 1) & 63) * 64;
        vreg0 = *(const int4*)&vb[((size_t)(s1 + 2 * sp)     * KV + kv) * DH + dc * 8];
        vreg1 = *(const int4*)&vb[((size_t)(s1 + 2 * sp + 1) * KV + kv) * DH + dc * 8];
        #pragma unroll
        for (int mt = 0; mt < 4; ++mt)
            #pragma unroll
            for (int kt = 0; kt < 2; ++kt)
                kn[mt][kt] = *(const bf16x8*)&kb[((size_t)(s1 + mt * 16 + c) * KV + kv) * DH + kt * 32 + quad * 8];

        // ---- St = K @ Q^T (per mt key-tile), exp2, pack, Ps write ----
        #pragma unroll
        for (int mt = 0; mt < 4; ++mt) {
            f32x4 st[2];
            #pragma unroll
            for (int qt = 0; qt < 2; ++qt) {
                f32x4 a = (f32x4){0.f, 0.f, 0.f, 0.f};
                a = __builtin_amdgcn_mfma_f32_16x16x32_bf16(kc[mt][0], qfrag[qt][0], a, 0, 0, 0);
                a = __builtin_amdgcn_mfma_f32_16x16x32_bf16(kc[mt][1], qfrag[qt][1], a, 0, 0, 0);
                st[qt] = a;
            }
            #pragma unroll
            for (int qt = 0; qt < 2; ++qt) {
                float p0 = EXP2F(st[qt][0]);
                float p1 = EXP2F(st[qt][1]);
                float p2 = EXP2F(st[qt][2]);
                float p3 = EXP2F(st[qt][3]);
                uint2 pk;
                pk.x = __builtin_amdgcn_perm(__float_as_uint(p1), __float_as_uint(p0), 0x07060302u);
                pk.y = __builtin_amdgcn_perm(__float_as_uint(p3), __float_as_uint(p2), 0x07060302u);
                *(uint2*)&PsW[(qt * 16 + c) * 64 + (((2 * mt + (quad >> 1)) ^ xr) << 3) + (quad & 1) * 4] = pk;
            }
        }

        // ---- read P A-frags (wave-private, no barrier) ----
        bf16x8 pf[2][2];
        #pragma unroll
        for (int qt = 0; qt < 2; ++qt)
            #pragma unroll
            for (int kt = 0; kt < 2; ++kt)
                pf[qt][kt] = *(const bf16x8*)&PsW[(qt * 16 + c) * 64 + (((kt * 4 + quad) ^ xr) << 3)];

        // ---- O += P @ V ; rowsums += P @ ones ----
        #pragma unroll
        for (int dt = 0; dt < 4; ++dt) {
            bf16x8 vf0 = *(const bf16x8*)&Vt[buf][dt * 16 + c][((0 * 4 + quad) ^ xr) << 3];
            bf16x8 vf1 = *(const bf16x8*)&Vt[buf][dt * 16 + c][((1 * 4 + quad) ^ xr) << 3];
            #pragma unroll
            for (int qt = 0; qt < 2; ++qt) {
                oacc[qt][dt] = __builtin_amdgcn_mfma_f32_16x16x32_bf16(pf[qt][0], vf0, oacc[qt][dt], 0, 0, 0);
                oacc[qt][dt] = __builtin_amdgcn_mfma_f32_16x16x32_bf16(pf[qt][1], vf1, oacc[qt][dt], 0, 0, 0);
            }
        }
        #pragma unroll
        for (int qt = 0; qt < 2; ++qt) {
            oones[qt] = __builtin_amdgcn_mfma_f32_16x16x32_bf16(pf[qt][0], ones8, oones[qt], 0, 0, 0);
            oones[qt] = __builtin_amdgcn_mfma_f32_16x16x32_bf16(pf[qt][1], ones8, oones[qt], 0, 0, 0);
        }
    };

    for (int it = 0; it < 64; it += 2) {
        step(it,     0, kA, kB);
        step(it + 1, 1, kB, kA);
    }

    // ---- normalize + store bf16 ----
    #pragma unroll
    for (int qt = 0; qt < 2; ++qt)
        #pragma unroll
        for (int r = 0; r < 4; ++r) {
            float inv = 1.0f / oones[qt][r];
            int row = q0 + qt * 16 + quad * 4 + r;
            #pragma unroll
            for (int dt = 0; dt < 4; ++dt)
                ob[(size_t)row * (H * DH) + h * DH + dt * 16 + c] = f2bf(oacc[qt][dt][r] * inv);
        }
}

// ---------------------------------------------------------------------------
extern "C" void kernel_launch(void* const* d_in, const int* in_sizes, int n_in,
                              void* d_out, int out_size, void* d_ws, size_t ws_size,
                              hipStream_t stream) {
    const float* x  = (const float*)d_in[0];
    const float* Wq = (const float*)d_in[1];
    const float* Wk = (const float*)d_in[2];
    const float* Wv = (const float*)d_in[3];
    const float* Wo = (const float*)d_in[4];
    float* out = (float*)d_out;

    // ---- workspace (~26.2 MB) ----
    char* ws = (char*)d_ws;
    unsigned short* xb    = (unsigned short*)ws;                      // 8.39 MB
    unsigned short* ob    = xb;                                       // aliases xb (dead after QKV GEMM)
    unsigned short* qb    = (unsigned short*)(ws + 8388608);          // 8.39 MB
    unsigned short* kb    = (unsigned short*)(ws + 16777216);         // 2.10 MB
    unsigned short* vb    = (unsigned short*)(ws + 18874368);         // 2.10 MB
    unsigned short* WqkvT = (unsigned short*)(ws + 20971520);         // 3.15 MB
    unsigned short* WoT   = (unsigned short*)(ws + 24117248);         // 2.10 MB

    dim3 blk(256);

    // 1) convert + transpose everything
    prep_kernel<<<6656, blk, 0, stream>>>(x, Wq, Wk, Wv, Wo, xb, WqkvT, WoT);

    // 2) fused QKV projection + RoPE + bf16 pack
    gemm_qkv_rope<<<dim3(12, 32), blk, 0, stream>>>(xb, WqkvT, qb, kb, vb);

    // 3) attention (writes bf16 ob over xb — dead)
    attn_mfma_kernel<<<dim3(L / 32, KV), blk, 0, stream>>>(qb, kb, vb, ob);

    // 4) output projection
    gemm_bf16<<<dim3(D / 128, L / 128), blk, 0, stream>>>(ob, WoT, out, L, D, D);
}

// Round 8
// 230.449 us; speedup vs baseline: 1.2202x; 1.2202x over previous
//
#include <hip/hip_runtime.h>
#include <math.h>

#define L 4096
#define D 1024
#define H 16
#define KV 4
#define DH 64
// G = H/KV = 4

typedef __attribute__((ext_vector_type(8))) short bf16x8;
typedef __attribute__((ext_vector_type(4))) float f32x4;

static __device__ __forceinline__ unsigned short f2bf(float f) {
    unsigned u = __float_as_uint(f);
    u = (u + 0x7FFF + ((u >> 16) & 1)) >> 16;   // RNE
    return (unsigned short)u;
}

#define EXP2F(x) __builtin_amdgcn_exp2f(x)

// async global->LDS, 16B per lane; dst must be wave-uniform base (HW: base + lane*16)
#define GLD16(src, dst) \
    __builtin_amdgcn_global_load_lds((__attribute__((address_space(1))) void*)(src), \
                                     (__attribute__((address_space(3))) void*)(dst), 16, 0, 0)

// ---------------------------------------------------------------------------
// prep: x fp32->bf16, and the four weight transposes (dst[n][k] bf16, K=1024).
// ---------------------------------------------------------------------------
__global__ __launch_bounds__(256) void prep_kernel(
        const float* __restrict__ x,  const float* __restrict__ Wq,
        const float* __restrict__ Wk, const float* __restrict__ Wv,
        const float* __restrict__ Wo,
        unsigned short* __restrict__ xb, unsigned short* __restrict__ WqkvT,
        unsigned short* __restrict__ WoT) {
    const int b = blockIdx.x, tid = threadIdx.x;
    if (b < 4096) {
        int i = (b * 256 + tid) * 4;
        float4 v = *(const float4*)&x[i];
        ushort4 o;
        o.x = f2bf(v.x); o.y = f2bf(v.y); o.z = f2bf(v.z); o.w = f2bf(v.w);
        *(ushort4*)&xb[i] = o;
        return;
    }
    __shared__ float t[32][33];
    const float* src; unsigned short* dst; int N, n0, k0;
    if (b < 5120)      { int tq = b - 4096; src = Wq; dst = WqkvT;                     N = 1024; n0 = (tq & 31) * 32; k0 = (tq >> 5) * 32; }
    else if (b < 5376) { int tq = b - 5120; src = Wk; dst = WqkvT + (size_t)1024*1024; N = 256;  n0 = (tq & 7)  * 32; k0 = (tq >> 3) * 32; }
    else if (b < 5632) { int tq = b - 5376; src = Wv; dst = WqkvT + (size_t)1280*1024; N = 256;  n0 = (tq & 7)  * 32; k0 = (tq >> 3) * 32; }
    else               { int tq = b - 5632; src = Wo; dst = WoT;                       N = 1024; n0 = (tq & 31) * 32; k0 = (tq >> 5) * 32; }
    const int tx = tid & 31, ty = tid >> 5;
    #pragma unroll
    for (int j = 0; j < 4; ++j)
        t[ty + 8 * j][tx] = src[(size_t)(k0 + ty + 8 * j) * N + n0 + tx];
    __syncthreads();
    #pragma unroll
    for (int j = 0; j < 4; ++j)
        dst[(size_t)(n0 + ty + 8 * j) * 1024 + k0 + tx] = f2bf(t[tx][ty + 8 * j]);
}

// ---------------------------------------------------------------------------
// bf16 MFMA GEMM (fp32 out) for the Wo projection.
// ---------------------------------------------------------------------------
__global__ __launch_bounds__(256) void gemm_bf16(const unsigned short* __restrict__ A,
                                                 const unsigned short* __restrict__ BT,
                                                 float* __restrict__ C,
                                                 int M, int N, int K) {
    __shared__ unsigned short As[128 * 32];
    __shared__ unsigned short Bs[128 * 32];

    const int tid  = threadIdx.x;
    const int w    = tid >> 6;
    const int lane = tid & 63;
    const int c    = lane & 15;
    const int quad = lane >> 4;
    const int wy = w >> 1, wx = w & 1;
    const int row0 = blockIdx.y * 128;
    const int col0 = blockIdx.x * 128;

    const int ld_row = w * 16 + (lane >> 2);
    const int ld_col = (lane & 3) * 8;

    f32x4 acc[4][4];
    #pragma unroll
    for (int mt = 0; mt < 4; ++mt)
        #pragma unroll
        for (int nt = 0; nt < 4; ++nt)
            acc[mt][nt] = (f32x4){0.f, 0.f, 0.f, 0.f};

    for (int k0 = 0; k0 < K; k0 += 32) {
        __syncthreads();
        GLD16(&A [(size_t)(row0 + ld_row)      * K + k0 + ld_col], &As[w * 512]);
        GLD16(&A [(size_t)(row0 + ld_row + 64) * K + k0 + ld_col], &As[w * 512 + 2048]);
        GLD16(&BT[(size_t)(col0 + ld_row)      * K + k0 + ld_col], &Bs[w * 512]);
        GLD16(&BT[(size_t)(col0 + ld_row + 64) * K + k0 + ld_col], &Bs[w * 512 + 2048]);
        __syncthreads();

        bf16x8 af[4], bfr[4];
        #pragma unroll
        for (int mt = 0; mt < 4; ++mt)
            af[mt] = *(const bf16x8*)&As[(wy * 64 + mt * 16 + c) * 32 + quad * 8];
        #pragma unroll
        for (int nt = 0; nt < 4; ++nt)
            bfr[nt] = *(const bf16x8*)&Bs[(wx * 64 + nt * 16 + c) * 32 + quad * 8];

        #pragma unroll
        for (int mt = 0; mt < 4; ++mt)
            #pragma unroll
            for (int nt = 0; nt < 4; ++nt)
                acc[mt][nt] = __builtin_amdgcn_mfma_f32_16x16x32_bf16(af[mt], bfr[nt], acc[mt][nt], 0, 0, 0);
    }

    #pragma unroll
    for (int mt = 0; mt < 4; ++mt)
        #pragma unroll
        for (int nt = 0; nt < 4; ++nt)
            #pragma unroll
            for (int r = 0; r < 4; ++r)
                C[(size_t)(row0 + wy * 64 + mt * 16 + quad * 4 + r) * N
                  + col0 + wx * 64 + nt * 16 + c] = acc[mt][nt][r];
}

// ---------------------------------------------------------------------------
// Fused QKV GEMM + RoPE epilogue. (unchanged from R6)
// ---------------------------------------------------------------------------
__global__ __launch_bounds__(256) void gemm_qkv_rope(
        const unsigned short* __restrict__ A,
        const unsigned short* __restrict__ BT,
        unsigned short* __restrict__ qb,
        unsigned short* __restrict__ kbuf,
        unsigned short* __restrict__ vbuf) {
    __shared__ unsigned short As[128 * 32];
    __shared__ unsigned short Bs[128 * 32];

    const int tid  = threadIdx.x;
    const int w    = tid >> 6;
    const int lane = tid & 63;
    const int c    = lane & 15;
    const int quad = lane >> 4;
    const int wy = w >> 1, wx = w & 1;
    const int row0 = blockIdx.y * 128;
    const int col0 = blockIdx.x * 128;

    const int ld_row = w * 16 + (lane >> 2);
    const int ld_col = (lane & 3) * 8;

    f32x4 acc[4][4];
    #pragma unroll
    for (int mt = 0; mt < 4; ++mt)
        #pragma unroll
        for (int nt = 0; nt < 4; ++nt)
            acc[mt][nt] = (f32x4){0.f, 0.f, 0.f, 0.f};

    for (int k0 = 0; k0 < 1024; k0 += 32) {
        __syncthreads();
        GLD16(&A [(size_t)(row0 + ld_row)      * 1024 + k0 + ld_col], &As[w * 512]);
        GLD16(&A [(size_t)(row0 + ld_row + 64) * 1024 + k0 + ld_col], &As[w * 512 + 2048]);
        GLD16(&BT[(size_t)(col0 + ld_row)      * 1024 + k0 + ld_col], &Bs[w * 512]);
        GLD16(&BT[(size_t)(col0 + ld_row + 64) * 1024 + k0 + ld_col], &Bs[w * 512 + 2048]);
        __syncthreads();

        bf16x8 af[4], bfr[4];
        #pragma unroll
        for (int mt = 0; mt < 4; ++mt)
            af[mt] = *(const bf16x8*)&As[(wy * 64 + mt * 16 + c) * 32 + quad * 8];
        #pragma unroll
        for (int nt = 0; nt < 4; ++nt)
            bfr[nt] = *(const bf16x8*)&Bs[(wx * 64 + nt * 16 + c) * 32 + quad * 8];

        #pragma unroll
        for (int mt = 0; mt < 4; ++mt)
            #pragma unroll
            for (int nt = 0; nt < 4; ++nt)
                acc[mt][nt] = __builtin_amdgcn_mfma_f32_16x16x32_bf16(af[mt], bfr[nt], acc[mt][nt], 0, 0, 0);
    }

    const int colb = col0 + wx * 64;
    if (colb < 1280) {
        unsigned short* dst; int hh, hstride; float scale;
        if (colb < 1024) { dst = qb;   hh = colb >> 6;          hstride = H;  scale = 0.18033688011112042f; }
        else             { dst = kbuf; hh = (colb - 1024) >> 6; hstride = KV; scale = 1.0f; }
        #pragma unroll
        for (int nt = 0; nt < 2; ++nt) {
            int d = nt * 16 + c;
            float invf = EXP2F((float)d * -0.4152410118609203f);
            #pragma unroll
            for (int mt = 0; mt < 4; ++mt)
                #pragma unroll
                for (int r = 0; r < 4; ++r) {
                    int l = row0 + wy * 64 + mt * 16 + quad * 4 + r;
                    float ang = (float)l * invf;
                    float sn = __sinf(ang), cs = __cosf(ang);
                    float x1 = acc[mt][nt][r], x2 = acc[mt][nt + 2][r];
                    dst[((size_t)l * hstride + hh) * DH + d]      = f2bf((x1 * cs - x2 * sn) * scale);
                    dst[((size_t)l * hstride + hh) * DH + d + 32] = f2bf((x2 * cs + x1 * sn) * scale);
                }
        }
    } else {
        int vh = (colb - 1280) >> 6;
        #pragma unroll
        for (int mt = 0; mt < 4; ++mt)
            #pragma unroll
            for (int nt = 0; nt < 4; ++nt)
                #pragma unroll
                for (int r = 0; r < 4; ++r) {
                    int l = row0 + wy * 64 + mt * 16 + quad * 4 + r;
                    vbuf[((size_t)l * KV + vh) * DH + nt * 16 + c] = f2bf(acc[mt][nt][r]);
                }
    }
}

// ---------------------------------------------------------------------------
// MFMA attention, key-split-in-block. Grid (64, KV), 512 thr = 8 waves.
// Wave w: head kv*4+(w&3), key-half g=w>>2 (2048 keys, 32 iters of 64),
// 64 q-rows per wave (R6 density: 72 MFMA per wave-iter). 8 waves/CU =
// 2/SIMD -> barrier/waitcnt latency hidden across waves.
// K direct global->regs (double-buffered). V staged per-group to swizzled
// LDS (double-buffered). Ps wave-private, XOR-swizzled. One barrier/iter.
// Epilogue: group 1 dumps fp32 partials to LDS; group 0 adds, normalizes,
// stores (softmax partial sums are exactly additive — no max rescaling).
// ---------------------------------------------------------------------------
__global__ __launch_bounds__(512, 2) void attn_mfma_kernel(
        const unsigned short* __restrict__ qb,
        const unsigned short* __restrict__ kb,
        const unsigned short* __restrict__ vb,
        unsigned short* __restrict__ ob) {
    __shared__ __align__(16) unsigned short Vt[2][2][64][64];  // [group][buf][d][key]
    __shared__ __align__(16) unsigned short Ps[8][64][64];     // [wave][q][key]

    const int tid  = threadIdx.x;
    const int w    = tid >> 6;        // 0..7
    const int lane = tid & 63;
    const int c    = lane & 15;
    const int quad = lane >> 4;
    const int g    = w >> 2;          // key group
    const int kv = blockIdx.y;
    const int h  = kv * 4 + (w & 3);
    const int q0 = blockIdx.x * 64;
    const int s_base = g * 2048;

    // Q B-frags: lane n=c -> q row q0+qt*16+c, elems d = kt*32+quad*8+j
    bf16x8 qfrag[4][2];
    #pragma unroll
    for (int qt = 0; qt < 4; ++qt)
        #pragma unroll
        for (int kt = 0; kt < 2; ++kt)
            qfrag[qt][kt] = *(const bf16x8*)&qb[((size_t)(q0 + qt * 16 + c) * H + h) * DH
                                                + kt * 32 + quad * 8];

    f32x4 oacc[4][4];     // [qt][dt]
    f32x4 oones[4];       // [qt] rowsums
    #pragma unroll
    for (int qt = 0; qt < 4; ++qt) {
        oones[qt] = (f32x4){0.f, 0.f, 0.f, 0.f};
        #pragma unroll
        for (int dt = 0; dt < 4; ++dt)
            oacc[qt][dt] = (f32x4){0.f, 0.f, 0.f, 0.f};
    }
    const short one_bf = (short)0x3F80;
    const bf16x8 ones8 = {one_bf, one_bf, one_bf, one_bf, one_bf, one_bf, one_bf, one_bf};

    const int tid8 = tid & 255;                 // id within group
    const int sp = tid8 & 31, dc = tid8 >> 5;   // V staging: keys (2sp,2sp+1), d-chunk dc*8
    unsigned short* PsW = &Ps[w][0][0];
    const int xr = c & 7;                       // swizzle xor

    // ---- prefetch iter 0 ----
    int4 vreg0 = *(const int4*)&vb[((size_t)(s_base + 2 * sp)     * KV + kv) * DH + dc * 8];
    int4 vreg1 = *(const int4*)&vb[((size_t)(s_base + 2 * sp + 1) * KV + kv) * DH + dc * 8];
    bf16x8 kA[4][2], kB[4][2];
    #pragma unroll
    for (int mt = 0; mt < 4; ++mt)
        #pragma unroll
        for (int kt = 0; kt < 2; ++kt)
            kA[mt][kt] = *(const bf16x8*)&kb[((size_t)(s_base + mt * 16 + c) * KV + kv) * DH + kt * 32 + quad * 8];

    auto step = [&](int it, int buf, bf16x8 kc[4][2], bf16x8 kn[4][2]) {
        // ---- write Vt[g][buf] (swizzled, conflict-free) ----
        {
            const unsigned* pa = (const unsigned*)&vreg0;
            const unsigned* pb = (const unsigned*)&vreg1;
            #pragma unroll
            for (int t = 0; t < 4; ++t) {
                unsigned lo = __builtin_amdgcn_perm(pb[t], pa[t], 0x05040100u);
                unsigned hi = __builtin_amdgcn_perm(pb[t], pa[t], 0x07060302u);
                int dl = dc * 8 + 2 * t, dh = dl + 1;
                *(unsigned*)&Vt[g][buf][dl][(((sp >> 2) ^ (dl & 7)) << 3) + 2 * (sp & 3)] = lo;
                *(unsigned*)&Vt[g][buf][dh][(((sp >> 2) ^ (dh & 7)) << 3) + 2 * (sp & 3)] = hi;
            }
        }
        __syncthreads();   // Vt[g][buf] visible; prior-iter reads complete

        // ---- prefetch next key-tile (overlaps compute below) ----
        int s1 = s_base + ((it + 1) & 31) * 64;
        vreg0 = *(const int4*)&vb[((size_t)(s1 + 2 * sp)     * KV + kv) * DH + dc * 8];
        vreg1 = *(const int4*)&vb[((size_t)(s1 + 2 * sp + 1) * KV + kv) * DH + dc * 8];
        #pragma unroll
        for (int mt = 0; mt < 4; ++mt)
            #pragma unroll
            for (int kt = 0; kt < 2; ++kt)
                kn[mt][kt] = *(const bf16x8*)&kb[((size_t)(s1 + mt * 16 + c) * KV + kv) * DH + kt * 32 + quad * 8];

        // ---- St = K @ Q^T (per mt key-tile), exp2, pack, Ps write ----
        #pragma unroll
        for (int mt = 0; mt < 4; ++mt) {
            f32x4 st[4];
            #pragma unroll
            for (int qt = 0; qt < 4; ++qt) {
                f32x4 a = (f32x4){0.f, 0.f, 0.f, 0.f};
                a = __builtin_amdgcn_mfma_f32_16x16x32_bf16(kc[mt][0], qfrag[qt][0], a, 0, 0, 0);
                a = __builtin_amdgcn_mfma_f32_16x16x32_bf16(kc[mt][1], qfrag[qt][1], a, 0, 0, 0);
                st[qt] = a;
            }
            #pragma unroll
            for (int qt = 0; qt < 4; ++qt) {
                float p0 = EXP2F(st[qt][0]);
                float p1 = EXP2F(st[qt][1]);
                float p2 = EXP2F(st[qt][2]);
                float p3 = EXP2F(st[qt][3]);
                uint2 pk;
                pk.x = __builtin_amdgcn_perm(__float_as_uint(p1), __float_as_uint(p0), 0x07060302u);
                pk.y = __builtin_amdgcn_perm(__float_as_uint(p3), __float_as_uint(p2), 0x07060302u);
                *(uint2*)&PsW[(qt * 16 + c) * 64 + (((2 * mt + (quad >> 1)) ^ xr) << 3) + (quad & 1) * 4] = pk;
            }
        }

        // ---- read P A-frags (wave-private, no barrier) ----
        bf16x8 pf[4][2];
        #pragma unroll
        for (int qt = 0; qt < 4; ++qt)
            #pragma unroll
            for (int kt = 0; kt < 2; ++kt)
                pf[qt][kt] = *(const bf16x8*)&PsW[(qt * 16 + c) * 64 + (((kt * 4 + quad) ^ xr) << 3)];

        // ---- O += P @ V ; rowsums += P @ ones ----
        #pragma unroll
        for (int dt = 0; dt < 4; ++dt) {
            bf16x8 vf0 = *(const bf16x8*)&Vt[g][buf][dt * 16 + c][((0 * 4 + quad) ^ xr) << 3];
            bf16x8 vf1 = *(const bf16x8*)&Vt[g][buf][dt * 16 + c][((1 * 4 + quad) ^ xr) << 3];
            #pragma unroll
            for (int qt = 0; qt < 4; ++qt) {
                oacc[qt][dt] = __builtin_amdgcn_mfma_f32_16x16x32_bf16(pf[qt][0], vf0, oacc[qt][dt], 0, 0, 0);
                oacc[qt][dt] = __builtin_amdgcn_mfma_f32_16x16x32_bf16(pf[qt][1], vf1, oacc[qt][dt], 0, 0, 0);
            }
        }
        #pragma unroll
        for (int qt = 0; qt < 4; ++qt) {
            oones[qt] = __builtin_amdgcn_mfma_f32_16x16x32_bf16(pf[qt][0], ones8, oones[qt], 0, 0, 0);
            oones[qt] = __builtin_amdgcn_mfma_f32_16x16x32_bf16(pf[qt][1], ones8, oones[qt], 0, 0, 0);
        }
    };

    for (int it = 0; it < 32; it += 2) {
        step(it,     0, kA, kB);
        step(it + 1, 1, kB, kA);
    }

    // ---- combine key-halves: group 1 dumps fp32 partials to LDS ----
    __syncthreads();   // all compute reads of Ps/Vt done
    if (g == 1) {
        float* dsto = (float*)&Ps[0][0][0] + (size_t)(w - 4) * 4096 + lane * 64;  // 16 KB/wave
        #pragma unroll
        for (int qt = 0; qt < 4; ++qt)
            #pragma unroll
            for (int dt = 0; dt < 4; ++dt)
                *(f32x4*)&dsto[qt * 16 + dt * 4] = oacc[qt][dt];
        float* dsts = (float*)&Vt[0][0][0][0] + (size_t)(w - 4) * 1024 + lane * 16;
        #pragma unroll
        for (int qt = 0; qt < 4; ++qt)
            *(f32x4*)&dsts[qt * 4] = oones[qt];
    }
    __syncthreads();
    if (g == 0) {
        const float* srco = (const float*)&Ps[0][0][0] + (size_t)w * 4096 + lane * 64;
        const float* srcs = (const float*)&Vt[0][0][0][0] + (size_t)w * 1024 + lane * 16;
        #pragma unroll
        for (int qt = 0; qt < 4; ++qt) {
            f32x4 po = *(const f32x4*)&srcs[qt * 4];
            oones[qt] += po;
            #pragma unroll
            for (int dt = 0; dt < 4; ++dt)
                oacc[qt][dt] += *(const f32x4*)&srco[qt * 16 + dt * 4];
        }
        #pragma unroll
        for (int qt = 0; qt < 4; ++qt)
            #pragma unroll
            for (int r = 0; r < 4; ++r) {
                float inv = 1.0f / oones[qt][r];
                int row = q0 + qt * 16 + quad * 4 + r;
                #pragma unroll
                for (int dt = 0; dt < 4; ++dt)
                    ob[(size_t)row * (H * DH) + h * DH + dt * 16 + c] = f2bf(oacc[qt][dt][r] * inv);
            }
    }
}

// ---------------------------------------------------------------------------
extern "C" void kernel_launch(void* const* d_in, const int* in_sizes, int n_in,
                              void* d_out, int out_size, void* d_ws, size_t ws_size,
                              hipStream_t stream) {
    const float* x  = (const float*)d_in[0];
    const float* Wq = (const float*)d_in[1];
    const float* Wk = (const float*)d_in[2];
    const float* Wv = (const float*)d_in[3];
    const float* Wo = (const float*)d_in[4];
    float* out = (float*)d_out;

    // ---- workspace (~26.2 MB) ----
    char* ws = (char*)d_ws;
    unsigned short* xb    = (unsigned short*)ws;                      // 8.39 MB
    unsigned short* ob    = xb;                                       // aliases xb (dead after QKV GEMM)
    unsigned short* qb    = (unsigned short*)(ws + 8388608);          // 8.39 MB
    unsigned short* kb    = (unsigned short*)(ws + 16777216);         // 2.10 MB
    unsigned short* vb    = (unsigned short*)(ws + 18874368);         // 2.10 MB
    unsigned short* WqkvT = (unsigned short*)(ws + 20971520);         // 3.15 MB
    unsigned short* WoT   = (unsigned short*)(ws + 24117248);         // 2.10 MB

    dim3 blk(256);

    // 1) convert + transpose everything
    prep_kernel<<<6656, blk, 0, stream>>>(x, Wq, Wk, Wv, Wo, xb, WqkvT, WoT);

    // 2) fused QKV projection + RoPE + bf16 pack
    gemm_qkv_rope<<<dim3(12, 32), blk, 0, stream>>>(xb, WqkvT, qb, kb, vb);

    // 3) attention (writes bf16 ob over xb — dead)
    attn_mfma_kernel<<<dim3(L / 64, KV), dim3(512), 0, stream>>>(qb, kb, vb, ob);

    // 4) output projection
    gemm_bf16<<<dim3(D / 128, L / 128), blk, 0, stream>>>(ob, WoT, out, L, D, D);
}